// Round 3
// baseline (408.705 us; speedup 1.0000x reference)
//
#include <hip/hip_runtime.h>
#include <math.h>

// N=20000 nodes, E=320000 edges (+N self loops), H=4 heads, HID=128, HC=512
#define NEG 0.2f
#define BN_EPS 1e-5f

typedef __attribute__((ext_vector_type(8))) short  bf16x8;
typedef __attribute__((ext_vector_type(4))) float  f32x4;

__device__ inline unsigned short f2b(float f) {
    unsigned int u = __float_as_uint(f);
    unsigned int r = (u + 0x7fffu + ((u >> 16) & 1u)) >> 16;
    return (unsigned short)r;
}
__device__ inline float b2f_lo(unsigned int u) { return __uint_as_float(u << 16); }
__device__ inline float b2f_hi(unsigned int u) { return __uint_as_float(u & 0xffff0000u); }

// ---------------- CSR build ----------------
__global__ void init_kernel(int* __restrict__ counts, int* __restrict__ cursor,
                            float* __restrict__ stats, int N) {
    int i = blockIdx.x * 256 + threadIdx.x;
    if (i < N) { counts[i] = 1; cursor[i] = 1; }  // slot 0 of each node = self loop
    if (i < 512) stats[i] = 0.f;
}

__global__ void hist_kernel(const int* __restrict__ dst, int* __restrict__ counts, int E) {
    int i = blockIdx.x * 256 + threadIdx.x;
    if (i < E) atomicAdd(&counts[dst[i]], 1);
}

// single-block exclusive scan (wave-shuffle based), counts[0..n-1] -> offsets[0..n]
__global__ void scan_kernel(const int* __restrict__ counts, int* __restrict__ offsets, int n) {
    __shared__ int wsums[16];
    __shared__ int tile_tot;
    __shared__ int carry_s;
    int tid = threadIdx.x, wid = tid >> 6, lane = tid & 63;
    if (tid == 0) carry_s = 0;
    __syncthreads();
    for (int base = 0; base < n; base += 1024) {
        int i = base + tid;
        int v = (i < n) ? counts[i] : 0;
        int incl = v;
#pragma unroll
        for (int off = 1; off < 64; off <<= 1) {
            int t = __shfl_up(incl, off);
            if (lane >= off) incl += t;
        }
        if (lane == 63) wsums[wid] = incl;
        __syncthreads();
        if (tid < 16) {
            int wv = wsums[tid];
            int winc = wv;
#pragma unroll
            for (int off = 1; off < 16; off <<= 1) {
                int t = __shfl_up(winc, off);
                if (tid >= off) winc += t;
            }
            wsums[tid] = winc - wv;     // exclusive wave offset
            if (tid == 15) tile_tot = winc;
        }
        __syncthreads();
        if (i < n) offsets[i] = carry_s + wsums[wid] + incl - v;
        __syncthreads();
        if (tid == 0) carry_s += tile_tot;
        __syncthreads();
    }
    if (tid == 0) offsets[n] = carry_s;
}

__global__ void scatter_kernel(const int* __restrict__ src, const int* __restrict__ dst,
                               const int* __restrict__ offsets, int* __restrict__ cursor,
                               int* __restrict__ csr_src, int E, int N) {
    int i = blockIdx.x * 256 + threadIdx.x;
    if (i < E) {
        int d = dst[i];
        int pos = offsets[d] + atomicAdd(&cursor[d], 1);
        csr_src[pos] = src[i];
    } else if (i < E + N) {
        int n = i - E;
        csr_src[offsets[n]] = n;   // self loop at slot 0
    }
}

// ---------------- f32 -> bf16 convert (x matrix) ----------------
__global__ void conv_bf16_kernel(const float* __restrict__ in, unsigned short* __restrict__ out,
                                 int total8) {
    int i = blockIdx.x * 256 + threadIdx.x;
    if (i >= total8) return;
    const float4* p = (const float4*)&in[(size_t)i * 8];
    float4 a = p[0], b = p[1];
    unsigned short o[8];
    o[0] = f2b(a.x); o[1] = f2b(a.y); o[2] = f2b(a.z); o[3] = f2b(a.w);
    o[4] = f2b(b.x); o[5] = f2b(b.y); o[6] = f2b(b.z); o[7] = f2b(b.w);
    *(uint4*)&out[(size_t)i * 8] = *(uint4*)o;
}

// ---------------- pack f32 weight W[K][Nsrc] into fused bf16 MFMA B-fragment buffer ----------------
// frag fn (global col-frag), ks: Bp[((fn*KS + ks)*64 + lane)*8 + j]
//   = bf16(W[ks*32 + (lane>>4)*8 + j][nb*16 + (lane&15)]),  fn = fn_off + nb
__global__ void pack_w_kernel(const float* __restrict__ W, unsigned short* __restrict__ Bp,
                              int K, int Nsrc, int fn_off) {
    int t = blockIdx.x * 256 + threadIdx.x;
    int KS = K >> 5;
    int total = KS * (Nsrc >> 4) * 64;
    if (t >= total) return;
    int lane = t & 63;
    int frag = t >> 6;
    int ks = frag % KS;
    int nb = frag / KS;
    int fn = fn_off + nb;
    int k0 = ks * 32 + (lane >> 4) * 8;
    int col = nb * 16 + (lane & 15);
    unsigned short o[8];
#pragma unroll
    for (int j = 0; j < 8; ++j) o[j] = f2b(W[(size_t)(k0 + j) * Nsrc + col]);
    *(uint4*)&Bp[(((size_t)fn * KS + ks) * 64 + lane) * 8] = *(uint4*)o;
}

__global__ void concat3_kernel(const float* __restrict__ a, int na,
                               const float* __restrict__ b, int nb,
                               const float* __restrict__ c, int nc,
                               float* __restrict__ o) {
    int i = blockIdx.x * 256 + threadIdx.x;
    int tot = na + nb + nc;
    if (i >= tot) return;
    float v;
    if (i < na) v = a[i];
    else if (i < na + nb) v = b[i - na];
    else v = c[i - na - nb];
    o[i] = v;
}

// ---------------- MFMA GEMM: out_bf16[M][Ncols] = A_bf16[M][K] @ Bp + bias ----------------
// 256 threads = 4 waves stacked in M; wave = 64 rows x 128 cols. grid (ceil(M/256), Ncols/128)
__global__ __launch_bounds__(256) void gemm_mfma2(
    const unsigned short* __restrict__ A, const unsigned short* __restrict__ Bp,
    const float* __restrict__ bias, unsigned short* __restrict__ out,
    int M, int Ncols, int K) {
    int wid = threadIdx.x >> 6, lane = threadIdx.x & 63;
    int brow = blockIdx.x * 256 + wid * 64;
    int cf0 = blockIdx.y * 8;       // col-frag base (8 frags = 128 cols)
    const int KS = K >> 5;

    f32x4 acc[4][8];
#pragma unroll
    for (int i = 0; i < 4; ++i)
#pragma unroll
        for (int j = 0; j < 8; ++j) acc[i][j] = (f32x4){0.f, 0.f, 0.f, 0.f};

    int rbase = brow + (lane & 15);
    int rA[4];
#pragma unroll
    for (int rf = 0; rf < 4; ++rf) {
        int r = rbase + rf * 16;
        rA[rf] = r < M ? r : M - 1;
    }
    int kofs = (lane >> 4) * 8;

    for (int ks = 0; ks < KS; ++ks) {
        int k0 = ks * 32 + kofs;
        bf16x8 a[4];
#pragma unroll
        for (int rf = 0; rf < 4; ++rf)
            a[rf] = *(const bf16x8*)&A[(size_t)rA[rf] * K + k0];
#pragma unroll
        for (int nb = 0; nb < 8; ++nb) {
            bf16x8 b = *(const bf16x8*)&Bp[(((size_t)(cf0 + nb) * KS + ks) * 64 + lane) * 8];
#pragma unroll
            for (int rf = 0; rf < 4; ++rf)
                acc[rf][nb] = __builtin_amdgcn_mfma_f32_16x16x32_bf16(a[rf], b, acc[rf][nb], 0, 0, 0);
        }
    }
    // epilogue: C/D col=lane&15, row=(lane>>4)*4+reg
    int crow = (lane >> 4) * 4;
    int ccol = lane & 15;
#pragma unroll
    for (int rf = 0; rf < 4; ++rf) {
#pragma unroll
        for (int nb = 0; nb < 8; ++nb) {
            int col = (cf0 + nb) * 16 + ccol;
            float bsv = bias[col];
#pragma unroll
            for (int reg = 0; reg < 4; ++reg) {
                int row = brow + rf * 16 + crow + reg;
                if (row < M) out[(size_t)row * Ncols + col] = f2b(acc[rf][nb][reg] + bsv);
            }
        }
    }
}

// ---------------- fused edge score + online softmax + aggregate (bf16 features) ----------------
// one wave per node; lane L holds elements [8L, 8L+8); xl = row base, xr = row base + 512
__global__ __launch_bounds__(256) void gat_edge_kernel(
    const int* __restrict__ offsets, const int* __restrict__ csr_src,
    const unsigned short* __restrict__ base, int stride,
    const float* __restrict__ att, const float* __restrict__ bvec,
    float* __restrict__ prebn, int N) {
    int lane = threadIdx.x & 63;
    int n = blockIdx.x * 4 + (threadIdx.x >> 6);
    if (n >= N) return;
    int start = offsets[n], end = offsets[n + 1];
    float xrv[8], attv[8], attn[8];
    {
        uint4 u = *(const uint4*)&base[(size_t)n * stride + 512 + lane * 8];
        xrv[0] = b2f_lo(u.x); xrv[1] = b2f_hi(u.x);
        xrv[2] = b2f_lo(u.y); xrv[3] = b2f_hi(u.y);
        xrv[4] = b2f_lo(u.z); xrv[5] = b2f_hi(u.z);
        xrv[6] = b2f_lo(u.w); xrv[7] = b2f_hi(u.w);
        const float4* q = (const float4*)&att[lane * 8];
        float4 u0 = q[0], u1 = q[1];
        attv[0] = u0.x; attv[1] = u0.y; attv[2] = u0.z; attv[3] = u0.w;
        attv[4] = u1.x; attv[5] = u1.y; attv[6] = u1.z; attv[7] = u1.w;
#pragma unroll
        for (int j = 0; j < 8; ++j) attn[j] = attv[j] * NEG;
    }
    float m = -INFINITY, d = 0.f;
    float acc[8] = {0, 0, 0, 0, 0, 0, 0, 0};
    int s0 = csr_src[start];
    uint4 ubuf = *(const uint4*)&base[(size_t)s0 * stride + lane * 8];
    for (int slot = start; slot < end; ++slot) {
        uint4 uc = ubuf;
        int nxt = slot + 1;
        if (nxt < end) {
            int s2 = csr_src[nxt];
            ubuf = *(const uint4*)&base[(size_t)s2 * stride + lane * 8];
        }
        float v[8];
        v[0] = b2f_lo(uc.x); v[1] = b2f_hi(uc.x);
        v[2] = b2f_lo(uc.y); v[3] = b2f_hi(uc.y);
        v[4] = b2f_lo(uc.z); v[5] = b2f_hi(uc.z);
        v[6] = b2f_lo(uc.w); v[7] = b2f_hi(uc.w);
        float p = 0.f;
#pragma unroll
        for (int j = 0; j < 8; ++j) {
            float t = v[j] + xrv[j];
            p = fmaf(attv[j], fmaxf(t, 0.f), fmaf(attn[j], fminf(t, 0.f), p));
        }
        // reduce within 16-lane head group
        p += __shfl_xor(p, 1);
        p += __shfl_xor(p, 2);
        p += __shfl_xor(p, 4);
        p += __shfl_xor(p, 8);
        if (__any(p > m)) {            // some head's max grew: full rescale path
            float mn = fmaxf(m, p);
            float scale = __expf(m - mn);  // exp(-inf)=0 on first edge
            float w = __expf(p - mn);
            d = d * scale + w;
#pragma unroll
            for (int j = 0; j < 8; ++j) acc[j] = fmaf(w, v[j], acc[j] * scale);
            m = mn;
        } else {                       // max unchanged anywhere: exact fast path
            float w = __expf(p - m);
            d += w;
#pragma unroll
            for (int j = 0; j < 8; ++j) acc[j] = fmaf(w, v[j], acc[j]);
        }
    }
    float inv = 1.f / d;
    float t[8];
#pragma unroll
    for (int j = 0; j < 8; ++j) {
        float u = acc[j] * inv;
        u += __shfl_xor(u, 16);    // sum over heads (h bit0)
        u += __shfl_xor(u, 32);    // (h bit1)
        t[j] = u;
    }
    if (lane < 16) {
        float o[8];
#pragma unroll
        for (int j = 0; j < 8; ++j) {
            int c = lane * 8 + j;
            float v2 = 0.25f * t[j] + bvec[c];
            o[j] = v2 > 0.f ? v2 : NEG * v2;   // leaky_relu before BN
        }
        float* dstp = &prebn[(size_t)n * 128 + lane * 8];
        *(float4*)&dstp[0] = make_float4(o[0], o[1], o[2], o[3]);
        *(float4*)&dstp[4] = make_float4(o[4], o[5], o[6], o[7]);
    }
}

// ---------------- BN stats + apply ----------------
__global__ void bn_stats_kernel(const float* __restrict__ v, float* __restrict__ stats, int N) {
    int c = threadIdx.x;  // 128
    int r0 = blockIdx.x * 160;
    int r1 = r0 + 160; if (r1 > N) r1 = N;
    float s = 0.f, ss = 0.f;
    for (int r = r0; r < r1; ++r) {
        float x = v[(size_t)r * 128 + c];
        s += x; ss += x * x;
    }
    atomicAdd(&stats[c], s);
    atomicAdd(&stats[128 + c], ss);
}

// skip16 (optional) is strided bf16; out16 non-null -> bf16 out, else f32 out
__global__ void bn_apply_kernel(const float* __restrict__ v, const float* __restrict__ stats,
                                const float* __restrict__ g, const float* __restrict__ be,
                                const unsigned short* __restrict__ skip16, int skipStride,
                                float* __restrict__ outf, unsigned short* __restrict__ out16,
                                int total, int N) {
    int i = blockIdx.x * 256 + threadIdx.x;
    if (i >= total) return;
    int c = i & 127;
    float invN = 1.f / (float)N;
    float mu = stats[c] * invN;
    float var = stats[128 + c] * invN - mu * mu;
    float rs = rsqrtf(var + BN_EPS);
    float x = (v[i] - mu) * rs * g[c] + be[c];
    if (skip16) x += b2f_lo((unsigned int)skip16[(size_t)(i >> 7) * skipStride + c]);
    if (out16) out16[i] = f2b(x);
    else outf[i] = x;
}

// ---------------- host ----------------
extern "C" void kernel_launch(void* const* d_in, const int* in_sizes, int n_in,
                              void* d_out, int out_size, void* d_ws, size_t ws_size,
                              hipStream_t stream) {
    const float* x    = (const float*)d_in[0];
    const int*   ei   = (const int*)d_in[1];
    const float* Wl0  = (const float*)d_in[2];
    const float* Wr0  = (const float*)d_in[3];
    const float* bl0  = (const float*)d_in[4];
    const float* br0  = (const float*)d_in[5];
    const float* att0 = (const float*)d_in[6];
    const float* b0   = (const float*)d_in[7];
    const float* g0   = (const float*)d_in[8];
    const float* be0  = (const float*)d_in[9];
    const float* Wl1  = (const float*)d_in[10];
    const float* Wr1  = (const float*)d_in[11];
    const float* bl1  = (const float*)d_in[12];
    const float* br1  = (const float*)d_in[13];
    const float* att1 = (const float*)d_in[14];
    const float* b1   = (const float*)d_in[15];
    const float* g1   = (const float*)d_in[16];
    const float* be1  = (const float*)d_in[17];
    const float* skW  = (const float*)d_in[18];
    const float* skb  = (const float*)d_in[19];

    const int K0 = 256, K1 = 128;
    int N = in_sizes[0] / K0;   // 20000
    int E = in_sizes[1] / 2;    // 320000
    int Etot = E + N;

    // workspace layout
    char* ws = (char*)d_ws;
    size_t off = 0;
    auto alloc = [&](size_t bytes) { size_t r = off; off += (bytes + 255) & ~(size_t)255; return r; };
    int*   counts  = (int*)(ws + alloc((size_t)(N + 1) * 4));
    int*   offsets = (int*)(ws + alloc((size_t)(N + 1) * 4));
    int*   cursor  = (int*)(ws + alloc((size_t)N * 4));
    int*   csr_src = (int*)(ws + alloc((size_t)Etot * 4));
    float* stats   = (float*)(ws + alloc(512 * 4));
    unsigned short* xb    = (unsigned short*)(ws + alloc((size_t)N * 256 * 2));
    unsigned short* l0out = (unsigned short*)(ws + alloc((size_t)N * 128 * 2));
    float* prebn   = (float*)(ws + alloc((size_t)N * 128 * 4));
    unsigned short* fused0 = (unsigned short*)(ws + alloc((size_t)N * 1152 * 2)); // [xl|xr|skip]
    unsigned short* fused1 = fused0;                                              // alias (dead after bn_apply0)
    unsigned short* Bp0 = (unsigned short*)(ws + alloc((size_t)(1152 / 16) * (K0 / 32) * 64 * 8 * 2));
    unsigned short* Bp1 = (unsigned short*)(ws + alloc((size_t)(1024 / 16) * (K1 / 32) * 64 * 8 * 2));
    float* bias0f = (float*)(ws + alloc(1152 * 4));
    float* bias1f = (float*)(ws + alloc(1024 * 4));
    float* outf = (float*)d_out;

    const int* src = ei;        // edge_index[0]
    const int* dst = ei + E;    // edge_index[1]

    // CSR build
    init_kernel<<<(N + 255) / 256, 256, 0, stream>>>(counts, cursor, stats, N);
    hist_kernel<<<(E + 255) / 256, 256, 0, stream>>>(dst, counts, E);
    scan_kernel<<<1, 1024, 0, stream>>>(counts, offsets, N);
    scatter_kernel<<<(Etot + 255) / 256, 256, 0, stream>>>(src, dst, offsets, cursor, csr_src, E, N);

    // input conversion + weight packing
    conv_bf16_kernel<<<((size_t)N * 256 / 8 + 255) / 256, 256, 0, stream>>>(x, xb, N * 256 / 8);
    pack_w_kernel<<<((K0 / 32) * (512 / 16) * 64 + 255) / 256, 256, 0, stream>>>(Wl0, Bp0, K0, 512, 0);
    pack_w_kernel<<<((K0 / 32) * (512 / 16) * 64 + 255) / 256, 256, 0, stream>>>(Wr0, Bp0, K0, 512, 32);
    pack_w_kernel<<<((K0 / 32) * (128 / 16) * 64 + 255) / 256, 256, 0, stream>>>(skW, Bp0, K0, 128, 64);
    pack_w_kernel<<<((K1 / 32) * (512 / 16) * 64 + 255) / 256, 256, 0, stream>>>(Wl1, Bp1, K1, 512, 0);
    pack_w_kernel<<<((K1 / 32) * (512 / 16) * 64 + 255) / 256, 256, 0, stream>>>(Wr1, Bp1, K1, 512, 32);
    concat3_kernel<<<(1152 + 255) / 256, 256, 0, stream>>>(bl0, 512, br0, 512, skb, 128, bias0f);
    concat3_kernel<<<(1024 + 255) / 256, 256, 0, stream>>>(bl1, 512, br1, 512, br1, 0, bias1f);

    // layer0: one fused GEMM  [xl | xr | skip]
    {
        dim3 g((N + 255) / 256, 1152 / 128);
        gemm_mfma2<<<g, 256, 0, stream>>>(xb, Bp0, bias0f, fused0, N, 1152, K0);
    }
    gat_edge_kernel<<<(N + 3) / 4, 256, 0, stream>>>(offsets, csr_src, fused0, 1152, att0, b0, prebn, N);
    bn_stats_kernel<<<(N + 159) / 160, 128, 0, stream>>>(prebn, stats, N);
    bn_apply_kernel<<<((size_t)N * 128 + 255) / 256, 256, 0, stream>>>(
        prebn, stats, g0, be0, fused0 + 1024, 1152, nullptr, l0out, N * 128, N);

    // layer1: one fused GEMM  [xl | xr]
    {
        dim3 g((N + 255) / 256, 1024 / 128);
        gemm_mfma2<<<g, 256, 0, stream>>>(l0out, Bp1, bias1f, fused1, N, 1024, K1);
    }
    gat_edge_kernel<<<(N + 3) / 4, 256, 0, stream>>>(offsets, csr_src, fused1, 1024, att1, b1, prebn, N);
    bn_stats_kernel<<<(N + 159) / 160, 128, 0, stream>>>(prebn, stats + 256, N);
    bn_apply_kernel<<<((size_t)N * 128 + 255) / 256, 256, 0, stream>>>(
        prebn, stats + 256, g1, be1, nullptr, 0, outf, nullptr, N * 128, N);
}